// Round 1
// baseline (459.418 us; speedup 1.0000x reference)
//
#include <hip/hip_runtime.h>
#include <hip/hip_bf16.h>

#define S_LEN 2048
#define E_DIM 512
#define D_DIM 64
#define H_NUM 8
#define B_NUM 2
#define BH_NUM 16
#define NQA 257   // 2*128+1 relative positions

// ---------------------------------------------------------------------------
// Kernel 1: projections  P[bh][s][d] = sum_e xs[b][s][e] * W[h][e][d]
// grid.x = BH*32 (64-row tiles), grid.y = 0/1/2 selects (w_q,Q),(w_k,K),(w_v,V)
// ---------------------------------------------------------------------------
__global__ __launch_bounds__(256) void proj_kernel(
    const float* __restrict__ xs,
    const float* __restrict__ w_q, const float* __restrict__ w_k,
    const float* __restrict__ w_v,
    float* __restrict__ Q, float* __restrict__ K, float* __restrict__ V)
{
    const int which = blockIdx.y;
    const float* W = (which == 0) ? w_q : (which == 1) ? w_k : w_v;
    float*       P = (which == 0) ? Q   : (which == 1) ? K   : V;

    const int bid = blockIdx.x;
    const int bh = bid >> 5, it = bid & 31;
    const int b = bh >> 3, h = bh & 7;
    const int i0 = it * 64;

    __shared__ float Xs[64][68];
    __shared__ float Ws[64][68];

    const int t = threadIdx.x;
    const int ir0 = (t >> 4) * 4;
    const int jc0 = (t & 15) * 4;

    float acc[4][4] = {};

    const float* xbase = xs + ((size_t)b * S_LEN + i0) * E_DIM;
    const float* wbase = W + (size_t)h * E_DIM * D_DIM;

    for (int ke = 0; ke < E_DIM; ke += 64) {
        #pragma unroll
        for (int k = 0; k < 4; ++k) {
            int idx = t + k * 256;
            int row = idx >> 4, c4 = (idx & 15) * 4;
            *(float4*)&Xs[row][c4] =
                *(const float4*)&xbase[(size_t)row * E_DIM + ke + c4];
            *(float4*)&Ws[row][c4] =
                *(const float4*)&wbase[(size_t)(ke + row) * D_DIM + c4];
        }
        __syncthreads();
        #pragma unroll 16
        for (int kk = 0; kk < 64; ++kk) {
            float4 bv = *(const float4*)&Ws[kk][jc0];
            float a0 = Xs[ir0 + 0][kk];
            float a1 = Xs[ir0 + 1][kk];
            float a2 = Xs[ir0 + 2][kk];
            float a3 = Xs[ir0 + 3][kk];
            acc[0][0] += a0 * bv.x; acc[0][1] += a0 * bv.y;
            acc[0][2] += a0 * bv.z; acc[0][3] += a0 * bv.w;
            acc[1][0] += a1 * bv.x; acc[1][1] += a1 * bv.y;
            acc[1][2] += a1 * bv.z; acc[1][3] += a1 * bv.w;
            acc[2][0] += a2 * bv.x; acc[2][1] += a2 * bv.y;
            acc[2][2] += a2 * bv.z; acc[2][3] += a2 * bv.w;
            acc[3][0] += a3 * bv.x; acc[3][1] += a3 * bv.y;
            acc[3][2] += a3 * bv.z; acc[3][3] += a3 * bv.w;
        }
        __syncthreads();
    }
    #pragma unroll
    for (int i = 0; i < 4; ++i) {
        float4 o;
        o.x = acc[i][0]; o.y = acc[i][1]; o.z = acc[i][2]; o.w = acc[i][3];
        *(float4*)&P[((size_t)bh * S_LEN + i0 + ir0 + i) * D_DIM + jc0] = o;
    }
}

// ---------------------------------------------------------------------------
// Kernel 2: QA[bh][s][r] = sum_d Q[bh][s][d] * a_k[r][d]   (r < 257)
// grid = BH*32 (64-row tiles)
// ---------------------------------------------------------------------------
__global__ __launch_bounds__(256) void qa_kernel(
    const float* __restrict__ Q, const float* __restrict__ a_k,
    float* __restrict__ QA)
{
    const int bid = blockIdx.x;
    const int bh = bid >> 5, it = bid & 31;
    const int i0 = it * 64;

    __shared__ float Qs[64][68];
    const int t = threadIdx.x;
    #pragma unroll
    for (int k = 0; k < 4; ++k) {
        int idx = t + k * 256;
        int row = idx >> 4, c4 = (idx & 15) * 4;
        *(float4*)&Qs[row][c4] =
            *(const float4*)&Q[((size_t)bh * S_LEN + i0 + row) * D_DIM + c4];
    }
    __syncthreads();

    const int row = t & 63;
    const int rg = t >> 6;  // 0..3
    float* outrow = QA + ((size_t)bh * S_LEN + i0 + row) * NQA;
    for (int r = rg; r < NQA; r += 4) {
        const float* ak = a_k + (size_t)r * D_DIM;
        float acc = 0.f;
        #pragma unroll
        for (int d4 = 0; d4 < 16; ++d4) {
            float4 qv = *(const float4*)&Qs[row][d4 * 4];
            float4 av = *(const float4*)&ak[d4 * 4];
            acc += qv.x * av.x + qv.y * av.y + qv.z * av.z + qv.w * av.w;
        }
        outrow[r] = acc;
    }
}

// ---------------------------------------------------------------------------
// Kernel 3: flash attention with relative bias.
// grid = BH*32; block = 256 (16x16 thread tile, each thread 4 rows x 4 cols)
// Z[bh][s][v] = w_o[h] * softmax_j((QK^T + bias)/8)[s,:] @ V
// ---------------------------------------------------------------------------
__global__ __launch_bounds__(256) void attn_kernel(
    const float* __restrict__ Q, const float* __restrict__ K,
    const float* __restrict__ V, const float* __restrict__ QA,
    const float* __restrict__ w_o, float* __restrict__ Z)
{
    const int bid = blockIdx.x;
    const int bh = bid >> 5, it = bid & 31;
    const int h = bh & 7;
    const int i0 = it * 64;

    __shared__ float QsT[64][68];  // [d][row]
    __shared__ float KsT[64][68];  // [d][col]
    __shared__ float Vs[64][68];   // [row][v]
    __shared__ float Ps[64][68];   // [row_i][col_j]

    const int t = threadIdx.x;
    const int ir0 = (t >> 4) * 4;  // query rows owned
    const int jc0 = (t & 15) * 4;  // S cols / V cols owned

    // stage Q transposed: QsT[d][row]
    #pragma unroll
    for (int k = 0; k < 4; ++k) {
        int idx = t + k * 256;
        int row = idx >> 4, d0 = (idx & 15) * 4;
        float4 qv = *(const float4*)&Q[((size_t)bh * S_LEN + i0 + row) * D_DIM + d0];
        QsT[d0 + 0][row] = qv.x;
        QsT[d0 + 1][row] = qv.y;
        QsT[d0 + 2][row] = qv.z;
        QsT[d0 + 3][row] = qv.w;
    }

    // per-row bias endpoints (r=0 / r=256) for out-of-band tiles
    const size_t qabase = ((size_t)bh * S_LEN + i0 + ir0) * NQA;
    float qa_lo[4], qa_hi[4];
    #pragma unroll
    for (int i = 0; i < 4; ++i) {
        qa_lo[i] = QA[qabase + (size_t)i * NQA + 0];
        qa_hi[i] = QA[qabase + (size_t)i * NQA + 256];
    }

    float rm[4], rl[4], acc[4][4];
    #pragma unroll
    for (int i = 0; i < 4; ++i) {
        rm[i] = -1e30f; rl[i] = 0.f;
        for (int j = 0; j < 4; ++j) acc[i][j] = 0.f;
    }

    for (int jt = 0; jt < 32; ++jt) {
        const int j0 = jt * 64;
        __syncthreads();  // prev PV done (also covers initial QsT staging)
        #pragma unroll
        for (int k = 0; k < 4; ++k) {
            int idx = t + k * 256;
            int row = idx >> 4, d0 = (idx & 15) * 4;
            float4 kv = *(const float4*)&K[((size_t)bh * S_LEN + j0 + row) * D_DIM + d0];
            KsT[d0 + 0][row] = kv.x;
            KsT[d0 + 1][row] = kv.y;
            KsT[d0 + 2][row] = kv.z;
            KsT[d0 + 3][row] = kv.w;
            *(float4*)&Vs[row][d0] =
                *(const float4*)&V[((size_t)bh * S_LEN + j0 + row) * D_DIM + d0];
        }
        __syncthreads();

        // S tile = Q K^T
        float s[4][4] = {};
        #pragma unroll 8
        for (int d = 0; d < 64; ++d) {
            float4 qv = *(const float4*)&QsT[d][ir0];
            float4 kv = *(const float4*)&KsT[d][jc0];
            s[0][0] += qv.x * kv.x; s[0][1] += qv.x * kv.y;
            s[0][2] += qv.x * kv.z; s[0][3] += qv.x * kv.w;
            s[1][0] += qv.y * kv.x; s[1][1] += qv.y * kv.y;
            s[1][2] += qv.y * kv.z; s[1][3] += qv.y * kv.w;
            s[2][0] += qv.z * kv.x; s[2][1] += qv.z * kv.y;
            s[2][2] += qv.z * kv.z; s[2][3] += qv.z * kv.w;
            s[3][0] += qv.w * kv.x; s[3][1] += qv.w * kv.y;
            s[3][2] += qv.w * kv.z; s[3][3] += qv.w * kv.w;
        }

        // add relative bias, scale by 1/8
        const int dmin = j0 - i0 - 63;
        const int dmax = j0 - i0 + 63;
        if (dmin >= 128) {
            #pragma unroll
            for (int i = 0; i < 4; ++i)
                #pragma unroll
                for (int j = 0; j < 4; ++j)
                    s[i][j] = (s[i][j] + qa_hi[i]) * 0.125f;
        } else if (dmax <= -128) {
            #pragma unroll
            for (int i = 0; i < 4; ++i)
                #pragma unroll
                for (int j = 0; j < 4; ++j)
                    s[i][j] = (s[i][j] + qa_lo[i]) * 0.125f;
        } else {
            #pragma unroll
            for (int i = 0; i < 4; ++i) {
                const float* qarow = QA + qabase + (size_t)i * NQA;
                #pragma unroll
                for (int j = 0; j < 4; ++j) {
                    int delta = (j0 + jc0 + j) - (i0 + ir0 + i);
                    int r = delta < -128 ? 0 : (delta > 128 ? 256 : delta + 128);
                    s[i][j] = (s[i][j] + qarow[r]) * 0.125f;
                }
            }
        }

        // online softmax update
        float mnew[4], corr[4];
        #pragma unroll
        for (int i = 0; i < 4; ++i) {
            float tm = fmaxf(fmaxf(s[i][0], s[i][1]), fmaxf(s[i][2], s[i][3]));
            tm = fmaxf(tm, __shfl_xor(tm, 1));
            tm = fmaxf(tm, __shfl_xor(tm, 2));
            tm = fmaxf(tm, __shfl_xor(tm, 4));
            tm = fmaxf(tm, __shfl_xor(tm, 8));
            mnew[i] = fmaxf(rm[i], tm);
            corr[i] = __expf(rm[i] - mnew[i]);
            rm[i] = mnew[i];
        }
        #pragma unroll
        for (int i = 0; i < 4; ++i) {
            float ts = 0.f;
            #pragma unroll
            for (int j = 0; j < 4; ++j) {
                float p = __expf(s[i][j] - mnew[i]);
                s[i][j] = p;
                ts += p;
            }
            ts += __shfl_xor(ts, 1);
            ts += __shfl_xor(ts, 2);
            ts += __shfl_xor(ts, 4);
            ts += __shfl_xor(ts, 8);
            rl[i] = rl[i] * corr[i] + ts;
            #pragma unroll
            for (int j = 0; j < 4; ++j) acc[i][j] *= corr[i];
            float4 pv;
            pv.x = s[i][0]; pv.y = s[i][1]; pv.z = s[i][2]; pv.w = s[i][3];
            *(float4*)&Ps[ir0 + i][jc0] = pv;
        }
        __syncthreads();

        // PV accumulate
        #pragma unroll 8
        for (int j = 0; j < 64; ++j) {
            float4 vv = *(const float4*)&Vs[j][jc0];
            float p0 = Ps[ir0 + 0][j];
            float p1 = Ps[ir0 + 1][j];
            float p2 = Ps[ir0 + 2][j];
            float p3 = Ps[ir0 + 3][j];
            acc[0][0] += p0 * vv.x; acc[0][1] += p0 * vv.y;
            acc[0][2] += p0 * vv.z; acc[0][3] += p0 * vv.w;
            acc[1][0] += p1 * vv.x; acc[1][1] += p1 * vv.y;
            acc[1][2] += p1 * vv.z; acc[1][3] += p1 * vv.w;
            acc[2][0] += p2 * vv.x; acc[2][1] += p2 * vv.y;
            acc[2][2] += p2 * vv.z; acc[2][3] += p2 * vv.w;
            acc[3][0] += p3 * vv.x; acc[3][1] += p3 * vv.y;
            acc[3][2] += p3 * vv.z; acc[3][3] += p3 * vv.w;
        }
    }

    const float woh = w_o[h];
    #pragma unroll
    for (int i = 0; i < 4; ++i) {
        float inv = woh / rl[i];
        float4 o;
        o.x = acc[i][0] * inv; o.y = acc[i][1] * inv;
        o.z = acc[i][2] * inv; o.w = acc[i][3] * inv;
        *(float4*)&Z[((size_t)bh * S_LEN + i0 + ir0 + i) * D_DIM + jc0] = o;
    }
}

// ---------------------------------------------------------------------------
// Kernel 4: combine heads  out[b][s][v] = sum_h Z[b*8+h][s][v]
// ---------------------------------------------------------------------------
__global__ __launch_bounds__(256) void combine_kernel(
    const float* __restrict__ Z, float* __restrict__ out)
{
    int idx = blockIdx.x * 256 + threadIdx.x;  // B*S*64 = 262144
    int v = idx & 63;
    int bs = idx >> 6;
    int b = bs >> 11, s = bs & 2047;
    float sum = 0.f;
    #pragma unroll
    for (int h = 0; h < 8; ++h)
        sum += Z[(((size_t)(b * 8 + h)) * S_LEN + s) * D_DIM + v];
    out[idx] = sum;
}

// ---------------------------------------------------------------------------
extern "C" void kernel_launch(void* const* d_in, const int* in_sizes, int n_in,
                              void* d_out, int out_size, void* d_ws, size_t ws_size,
                              hipStream_t stream)
{
    const float* xs  = (const float*)d_in[0];
    const float* w_q = (const float*)d_in[1];
    const float* w_k = (const float*)d_in[2];
    const float* w_v = (const float*)d_in[3];
    const float* w_o = (const float*)d_in[4];
    const float* a_k = (const float*)d_in[5];
    float* out = (float*)d_out;

    float* ws = (float*)d_ws;
    const size_t QKV = (size_t)BH_NUM * S_LEN * D_DIM;  // 2,097,152
    float* Q  = ws;
    float* K  = ws + QKV;
    float* V  = ws + 2 * QKV;
    float* QA = ws + 3 * QKV;                            // BH*S*257
    float* Z  = QA + (size_t)BH_NUM * S_LEN * NQA;

    proj_kernel<<<dim3(BH_NUM * 32, 3), 256, 0, stream>>>(xs, w_q, w_k, w_v, Q, K, V);
    qa_kernel<<<BH_NUM * 32, 256, 0, stream>>>(Q, a_k, QA);
    attn_kernel<<<BH_NUM * 32, 256, 0, stream>>>(Q, K, V, QA, w_o, Z);
    combine_kernel<<<(B_NUM * S_LEN * D_DIM) / 256, 256, 0, stream>>>(Z, out);
}

// Round 2
// 112.377 us; speedup vs baseline: 4.0882x; 4.0882x over previous
//
#include <hip/hip_runtime.h>
#include <hip/hip_bf16.h>

#define S_LEN 2048
#define E_DIM 512
#define D_DIM 64
#define H_NUM 8
#define B_NUM 2
#define BH_NUM 16
#define NQA 257

typedef _Float16 half8 __attribute__((ext_vector_type(8)));
typedef _Float16 half4 __attribute__((ext_vector_type(4)));
typedef float f32x16 __attribute__((ext_vector_type(16)));

static __device__ __forceinline__ f32x16 MFMA(half8 a, half8 b, f32x16 c) {
    return __builtin_amdgcn_mfma_f32_32x32x16_f16(a, b, c, 0, 0, 0);
}
static __device__ __forceinline__ f32x16 ZERO16() {
    f32x16 z;
    #pragma unroll
    for (int i = 0; i < 16; ++i) z[i] = 0.f;
    return z;
}

// ---------------------------------------------------------------------------
// cast xs (fp32) -> Xh (fp16)
// ---------------------------------------------------------------------------
__global__ __launch_bounds__(256) void cast_x_kernel(
    const float* __restrict__ xs, _Float16* __restrict__ Xh)
{
    const int idx = (blockIdx.x * 256 + threadIdx.x) * 8;  // total 2*2048*512
    float4 a = *(const float4*)&xs[idx];
    float4 b = *(const float4*)&xs[idx + 4];
    half8 o;
    o[0] = (_Float16)a.x; o[1] = (_Float16)a.y; o[2] = (_Float16)a.z; o[3] = (_Float16)a.w;
    o[4] = (_Float16)b.x; o[5] = (_Float16)b.y; o[6] = (_Float16)b.z; o[7] = (_Float16)b.w;
    *(half8*)&Xh[idx] = o;
}

// ---------------------------------------------------------------------------
// cast + transpose weights -> Wht[type][h][n=64][k=512] fp16
// type0 (w_q) scaled 0.125, type2 (w_v) scaled w_o[h]
// grid (8 ktiles, 8 h, 3 type)
// ---------------------------------------------------------------------------
__global__ __launch_bounds__(256) void cast_w_kernel(
    const float* __restrict__ w_q, const float* __restrict__ w_k,
    const float* __restrict__ w_v, const float* __restrict__ w_o,
    _Float16* __restrict__ Wht)
{
    __shared__ float T[64][68];
    const int kt = blockIdx.x, h = blockIdx.y, type = blockIdx.z;
    const float* W = (type == 0) ? w_q : (type == 1) ? w_k : w_v;
    const float scale = (type == 0) ? 0.125f : (type == 2 ? w_o[h] : 1.0f);
    const int t = threadIdx.x;
    const int kr = t >> 2, nseg = (t & 3) * 16;
    #pragma unroll
    for (int i = 0; i < 4; ++i)
        *(float4*)&T[kr][nseg + 4 * i] =
            *(const float4*)&W[((size_t)h * 512 + kt * 64 + kr) * 64 + nseg + 4 * i];
    __syncthreads();
    const int nr = t >> 2, kseg = (t & 3) * 16;
    _Float16* dst = Wht + ((size_t)(type * 8 + h) * 64 + nr) * 512 + kt * 64 + kseg;
    #pragma unroll
    for (int i = 0; i < 2; ++i) {
        half8 o;
        #pragma unroll
        for (int j = 0; j < 8; ++j) o[j] = (_Float16)(T[kseg + 8 * i + j][nr] * scale);
        *(half8*)&dst[8 * i] = o;
    }
}

// ---------------------------------------------------------------------------
// cast a_k -> fp16 (16448 elements = 2056 threads * 8)
// ---------------------------------------------------------------------------
__global__ __launch_bounds__(256) void cast_ak_kernel(
    const float* __restrict__ a_k, _Float16* __restrict__ akh)
{
    const int idx = (blockIdx.x * 256 + threadIdx.x) * 8;
    if (idx >= NQA * 64) return;
    float4 a = *(const float4*)&a_k[idx];
    float4 b = *(const float4*)&a_k[idx + 4];
    half8 o;
    o[0] = (_Float16)a.x; o[1] = (_Float16)a.y; o[2] = (_Float16)a.z; o[3] = (_Float16)a.w;
    o[4] = (_Float16)b.x; o[5] = (_Float16)b.y; o[6] = (_Float16)b.z; o[7] = (_Float16)b.w;
    *(half8*)&akh[idx] = o;
}

// ---------------------------------------------------------------------------
// MFMA projections: out[2048x64] = Xh[b] * Wht[type][h]^T   (K=512)
// grid (16 mtiles, 16 bh, 3 type), block 256 (4 waves x 32 rows)
// type0 -> Qh (scaled), type1 -> Kh, type2 -> Vt (transposed [v][s])
// ---------------------------------------------------------------------------
__global__ __launch_bounds__(256) void proj_mfma_kernel(
    const _Float16* __restrict__ Xh, const _Float16* __restrict__ Wht,
    _Float16* __restrict__ Qh, _Float16* __restrict__ Kh,
    _Float16* __restrict__ Vt)
{
    __shared__ _Float16 Xlds[2][128][72];
    __shared__ _Float16 Wlds[2][64][72];   // reused as Olds[128][72] in epilogue

    const int mt = blockIdx.x, bh = blockIdx.y, type = blockIdx.z;
    const int b = bh >> 3, h = bh & 7;
    const int m0 = mt * 128;
    const int t = threadIdx.x, wid = t >> 6, lane = t & 63;
    const int lq = lane & 31, lh = lane >> 5;

    const _Float16* W = Wht + (size_t)(type * 8 + h) * 64 * 512;
    const _Float16* X = Xh + ((size_t)b * S_LEN + m0) * 512;

    const int xrow = t >> 1, xseg = (t & 1) * 32;
    const int wrow = t >> 2, wseg = (t & 3) * 16;

    // prologue: stage chunk 0
    #pragma unroll
    for (int i = 0; i < 4; ++i)
        *(half8*)&Xlds[0][xrow][xseg + 8 * i] =
            *(const half8*)&X[(size_t)xrow * 512 + xseg + 8 * i];
    #pragma unroll
    for (int i = 0; i < 2; ++i)
        *(half8*)&Wlds[0][wrow][wseg + 8 * i] =
            *(const half8*)&W[(size_t)wrow * 512 + wseg + 8 * i];
    __syncthreads();

    f32x16 acc[2];
    acc[0] = ZERO16(); acc[1] = ZERO16();
    int cur = 0;
    for (int c = 0; c < 8; ++c) {
        half8 xst[4], wst[2];
        if (c < 7) {
            const int k0 = (c + 1) * 64;
            #pragma unroll
            for (int i = 0; i < 4; ++i)
                xst[i] = *(const half8*)&X[(size_t)xrow * 512 + k0 + xseg + 8 * i];
            #pragma unroll
            for (int i = 0; i < 2; ++i)
                wst[i] = *(const half8*)&W[(size_t)wrow * 512 + k0 + wseg + 8 * i];
        }
        #pragma unroll
        for (int kc = 0; kc < 4; ++kc) {
            half8 a  = *(const half8*)&Xlds[cur][wid * 32 + lq][kc * 16 + lh * 8];
            half8 b0 = *(const half8*)&Wlds[cur][lq][kc * 16 + lh * 8];
            half8 b1 = *(const half8*)&Wlds[cur][32 + lq][kc * 16 + lh * 8];
            acc[0] = MFMA(a, b0, acc[0]);
            acc[1] = MFMA(a, b1, acc[1]);
        }
        if (c < 7) {
            #pragma unroll
            for (int i = 0; i < 4; ++i)
                *(half8*)&Xlds[cur ^ 1][xrow][xseg + 8 * i] = xst[i];
            #pragma unroll
            for (int i = 0; i < 2; ++i)
                *(half8*)&Wlds[cur ^ 1][wrow][wseg + 8 * i] = wst[i];
        }
        __syncthreads();
        cur ^= 1;
    }

    // epilogue: bounce through LDS (reuse Wlds as Olds[128][72])
    _Float16* ob = &Wlds[0][0][0];
    #pragma unroll
    for (int n = 0; n < 2; ++n)
        #pragma unroll
        for (int r = 0; r < 16; ++r) {
            int row = wid * 32 + (r & 3) + ((r >> 2) << 3) + (lh << 2);
            ob[row * 72 + n * 32 + lq] = (_Float16)acc[n][r];
        }
    __syncthreads();

    if (type == 2) {
        const int v = t >> 2, sseg = (t & 3) * 32;
        _Float16* dst = Vt + ((size_t)bh * 64 + v) * S_LEN + m0 + sseg;
        #pragma unroll
        for (int i = 0; i < 4; ++i) {
            half8 o;
            #pragma unroll
            for (int j = 0; j < 8; ++j) o[j] = ob[(sseg + 8 * i + j) * 72 + v];
            *(half8*)&dst[8 * i] = o;
        }
    } else {
        _Float16* P = (type == 0) ? Qh : Kh;
        const int row = t >> 1, seg = (t & 1) * 32;
        _Float16* dst = P + ((size_t)bh * S_LEN + m0 + row) * 64 + seg;
        #pragma unroll
        for (int i = 0; i < 4; ++i)
            *(half8*)&dst[8 * i] = *(const half8*)&ob[row * 72 + seg + 8 * i];
    }
}

// ---------------------------------------------------------------------------
// MFMA QA: QA[bh][s][r] = Qh[bh][s][:] . akh[r][:]   (fp32 out, K=64)
// grid (16 mtiles, 16 bh), block 256
// ---------------------------------------------------------------------------
__global__ __launch_bounds__(256) void qa_mfma_kernel(
    const _Float16* __restrict__ Qh, const _Float16* __restrict__ akh,
    float* __restrict__ QA)
{
    __shared__ _Float16 ak[288][72];
    const int m0 = blockIdx.x * 128, bh = blockIdx.y;
    const int t = threadIdx.x, wid = t >> 6, lane = t & 63;
    const int lq = lane & 31, lh = lane >> 5;

    for (int r = t; r < 288; r += 256) {
        if (r < NQA) {
            #pragma unroll
            for (int i = 0; i < 8; ++i)
                *(half8*)&ak[r][8 * i] = *(const half8*)&akh[(size_t)r * 64 + 8 * i];
        } else {
            half8 z = {};
            #pragma unroll
            for (int i = 0; i < 8; ++i) *(half8*)&ak[r][8 * i] = z;
        }
    }
    __syncthreads();

    const int qg = m0 + wid * 32 + lq;
    half8 qfr[4];
    #pragma unroll
    for (int kc = 0; kc < 4; ++kc)
        qfr[kc] = *(const half8*)&Qh[((size_t)bh * S_LEN + qg) * 64 + kc * 16 + lh * 8];

    for (int nsub = 0; nsub < 9; ++nsub) {
        f32x16 acc = ZERO16();
        #pragma unroll
        for (int kc = 0; kc < 4; ++kc) {
            half8 bf = *(const half8*)&ak[nsub * 32 + lq][kc * 16 + lh * 8];
            acc = MFMA(qfr[kc], bf, acc);
        }
        const int col = nsub * 32 + lq;
        if (col < NQA) {
            #pragma unroll
            for (int r = 0; r < 16; ++r) {
                int row = m0 + wid * 32 + (r & 3) + ((r >> 2) << 3) + (lh << 2);
                QA[((size_t)bh * S_LEN + row) * NQA + col] = acc[r];
            }
        }
    }
}

// ---------------------------------------------------------------------------
// Flash attention, swapped-operand MFMA. grid 256 (XCD-remapped), block 256.
// Each block: 128 q-rows (4 waves x 32), loops 32 k-tiles of 64.
// Writes Zt[bh][v][s] fp32 (w_o already folded into V).
// ---------------------------------------------------------------------------
__global__ __launch_bounds__(256) void attn_kernel(
    const _Float16* __restrict__ Qh, const _Float16* __restrict__ Kh,
    const _Float16* __restrict__ Vt, const float* __restrict__ QA,
    float* __restrict__ Zt)
{
    __shared__ _Float16 Klds[2][64][72];
    __shared__ _Float16 Vlds[2][64][72];
    __shared__ _Float16 Plds[4][32][72];

    // XCD-aware remap: 16 i-tiles of one bh stay on ~one XCD (2 bh per XCD)
    const int bid0 = blockIdx.x;
    const int nb = (bid0 & 7) * 32 + (bid0 >> 3);
    const int bh = nb >> 4, itile = nb & 15;
    const int i0 = itile * 128;

    const int t = threadIdx.x, wid = t >> 6, lane = t & 63;
    const int lq = lane & 31, lh = lane >> 5;
    const int i0w = i0 + wid * 32;
    const int qg = i0w + lq;

    // Q fragments (B-operand of swapped QK^T), pre-scaled by 1/8 already
    half8 qf[4];
    #pragma unroll
    for (int kc = 0; kc < 4; ++kc)
        qf[kc] = *(const half8*)&Qh[((size_t)bh * S_LEN + qg) * 64 + kc * 16 + lh * 8];

    const float* qaRow = QA + ((size_t)bh * S_LEN + qg) * NQA;
    const float qa_lo = qaRow[0];
    const float qa_hi = qaRow[256];

    float rm = -1e30f, rl = 0.f;
    f32x16 acco[2];
    acco[0] = ZERO16(); acco[1] = ZERO16();

    // staging layout: per thread 32B of K-tile and 32B of Vt-tile
    const int srow = t >> 2, sseg = (t & 3) * 16;
    const size_t kbase = ((size_t)bh * S_LEN) * 64;
    const size_t vbase = ((size_t)bh * 64 + srow) * S_LEN;

    // prologue: stage tile 0
    {
        #pragma unroll
        for (int i = 0; i < 2; ++i) {
            *(half8*)&Klds[0][srow][sseg + 8 * i] =
                *(const half8*)&Kh[kbase + (size_t)srow * 64 + sseg + 8 * i];
            *(half8*)&Vlds[0][srow][sseg + 8 * i] =
                *(const half8*)&Vt[vbase + sseg + 8 * i];
        }
    }
    __syncthreads();

    int cur = 0;
    for (int jt = 0; jt < 32; ++jt) {
        const int j0 = jt * 64;
        half8 kst[2], vst[2];
        if (jt < 31) {
            const int j0n = j0 + 64;
            #pragma unroll
            for (int i = 0; i < 2; ++i) {
                kst[i] = *(const half8*)&Kh[kbase + (size_t)(j0n + srow) * 64 + sseg + 8 * i];
                vst[i] = *(const half8*)&Vt[vbase + j0n + sseg + 8 * i];
            }
        }

        // S^T = K . Q^T  (rows = keys, cols = q)
        f32x16 accs[2];
        accs[0] = ZERO16(); accs[1] = ZERO16();
        #pragma unroll
        for (int kc = 0; kc < 4; ++kc) {
            half8 k0 = *(const half8*)&Klds[cur][lq][kc * 16 + lh * 8];
            half8 k1 = *(const half8*)&Klds[cur][32 + lq][kc * 16 + lh * 8];
            accs[0] = MFMA(k0, qf[kc], accs[0]);
            accs[1] = MFMA(k1, qf[kc], accs[1]);
        }

        // add relative bias
        const bool allhi = (j0 >= i0w + 159);
        const bool alllo = (j0 + 63 <= i0w - 128);
        if (allhi || alllo) {
            const float bias = allhi ? qa_hi : qa_lo;
            #pragma unroll
            for (int m = 0; m < 2; ++m)
                #pragma unroll
                for (int r = 0; r < 16; ++r) accs[m][r] += bias;
        } else {
            #pragma unroll
            for (int m = 0; m < 2; ++m)
                #pragma unroll
                for (int r = 0; r < 16; ++r) {
                    int key = m * 32 + (r & 3) + ((r >> 2) << 3) + (lh << 2);
                    int delta = j0 + key - qg;
                    int idx = min(max(delta, -128), 128) + 128;
                    accs[m][r] += qaRow[idx];
                }
        }

        // online softmax (per lane owns q-row lq; halves synced via xor 32)
        float tmax = -1e30f;
        #pragma unroll
        for (int m = 0; m < 2; ++m)
            #pragma unroll
            for (int r = 0; r < 16; ++r) tmax = fmaxf(tmax, accs[m][r]);
        tmax = fmaxf(tmax, __shfl_xor(tmax, 32));
        const float mnew = fmaxf(rm, tmax);
        const float corr = __expf(rm - mnew);
        rm = mnew;

        float psum = 0.f;
        #pragma unroll
        for (int m = 0; m < 2; ++m)
            #pragma unroll
            for (int r = 0; r < 16; ++r) {
                float p = __expf(accs[m][r] - mnew);
                accs[m][r] = p;
                psum += p;
            }
        psum += __shfl_xor(psum, 32);
        rl = rl * corr + psum;
        #pragma unroll
        for (int n = 0; n < 2; ++n)
            #pragma unroll
            for (int r = 0; r < 16; ++r) acco[n][r] *= corr;

        // P -> per-wave LDS (fp16), keys (r&3) consecutive per write
        #pragma unroll
        for (int m = 0; m < 2; ++m)
            #pragma unroll
            for (int rb = 0; rb < 4; ++rb) {
                half4 hp;
                hp[0] = (_Float16)accs[m][rb * 4 + 0];
                hp[1] = (_Float16)accs[m][rb * 4 + 1];
                hp[2] = (_Float16)accs[m][rb * 4 + 2];
                hp[3] = (_Float16)accs[m][rb * 4 + 3];
                *(half4*)&Plds[wid][lq][m * 32 + rb * 8 + lh * 4] = hp;
            }
        // wave-synchronous LDS: drain writes before cross-lane reads
        asm volatile("s_waitcnt lgkmcnt(0)" ::: "memory");
        __builtin_amdgcn_sched_barrier(0);

        // O^T += Vt . P^T   (rows = v, cols = q)
        #pragma unroll
        for (int kc = 0; kc < 4; ++kc) {
            half8 pf = *(const half8*)&Plds[wid][lq][kc * 16 + lh * 8];
            half8 v0 = *(const half8*)&Vlds[cur][lq][kc * 16 + lh * 8];
            half8 v1 = *(const half8*)&Vlds[cur][32 + lq][kc * 16 + lh * 8];
            acco[0] = MFMA(v0, pf, acco[0]);
            acco[1] = MFMA(v1, pf, acco[1]);
        }

        if (jt < 31) {
            #pragma unroll
            for (int i = 0; i < 2; ++i) {
                *(half8*)&Klds[cur ^ 1][srow][sseg + 8 * i] = kst[i];
                *(half8*)&Vlds[cur ^ 1][srow][sseg + 8 * i] = vst[i];
            }
        }
        __syncthreads();
        cur ^= 1;
    }

    const float inv = 1.0f / rl;
    #pragma unroll
    for (int n = 0; n < 2; ++n)
        #pragma unroll
        for (int r = 0; r < 16; ++r) {
            int v = n * 32 + (r & 3) + ((r >> 2) << 3) + (lh << 2);
            Zt[((size_t)bh * 64 + v) * S_LEN + i0w + lq] = acco[n][r] * inv;
        }
}

// ---------------------------------------------------------------------------
// combine: out[b][s][v] = sum_h Zt[b*8+h][v][s]   (w_o folded already)
// grid 256 (2 b x 128 s-chunks of 16)
// ---------------------------------------------------------------------------
__global__ __launch_bounds__(256) void combine_kernel(
    const float* __restrict__ Zt, float* __restrict__ out)
{
    const int bid = blockIdx.x;
    const int b = bid >> 7, s0 = (bid & 127) * 16;
    const int t = threadIdx.x;
    const int sl = t & 15, vb = (t >> 4) * 4;
    float a0 = 0, a1 = 0, a2 = 0, a3 = 0;
    #pragma unroll
    for (int h = 0; h < 8; ++h) {
        const float* z = Zt + (size_t)(b * 8 + h) * 64 * S_LEN;
        a0 += z[(size_t)(vb + 0) * S_LEN + s0 + sl];
        a1 += z[(size_t)(vb + 1) * S_LEN + s0 + sl];
        a2 += z[(size_t)(vb + 2) * S_LEN + s0 + sl];
        a3 += z[(size_t)(vb + 3) * S_LEN + s0 + sl];
    }
    float4 o = {a0, a1, a2, a3};
    *(float4*)&out[((size_t)b * S_LEN + s0 + sl) * 64 + vb] = o;
}

// ---------------------------------------------------------------------------
extern "C" void kernel_launch(void* const* d_in, const int* in_sizes, int n_in,
                              void* d_out, int out_size, void* d_ws, size_t ws_size,
                              hipStream_t stream)
{
    const float* xs  = (const float*)d_in[0];
    const float* w_q = (const float*)d_in[1];
    const float* w_k = (const float*)d_in[2];
    const float* w_v = (const float*)d_in[3];
    const float* w_o = (const float*)d_in[4];
    const float* a_k = (const float*)d_in[5];
    float* out = (float*)d_out;

    char* w = (char*)d_ws;
    _Float16* Xh  = (_Float16*)w;                       w += (size_t)B_NUM * S_LEN * E_DIM * 2;      // 4 MB
    _Float16* Wht = (_Float16*)w;                       w += (size_t)3 * H_NUM * 64 * 512 * 2;       // 1.5 MB
    _Float16* akh = (_Float16*)w;                       w += 33024;
    _Float16* Qh  = (_Float16*)w;                       w += (size_t)BH_NUM * S_LEN * 64 * 2;        // 4 MB
    _Float16* Kh  = (_Float16*)w;                       w += (size_t)BH_NUM * S_LEN * 64 * 2;
    _Float16* Vt  = (_Float16*)w;                       w += (size_t)BH_NUM * S_LEN * 64 * 2;
    float*    QA  = (float*)w;                          w += (size_t)BH_NUM * S_LEN * NQA * 4;       // 33.7 MB
    float*    Zt  = (float*)w;                                                                       // 8 MB

    cast_x_kernel<<<1024, 256, 0, stream>>>(xs, Xh);
    cast_w_kernel<<<dim3(8, 8, 3), 256, 0, stream>>>(w_q, w_k, w_v, w_o, Wht);
    cast_ak_kernel<<<9, 256, 0, stream>>>(a_k, akh);
    proj_mfma_kernel<<<dim3(16, 16, 3), 256, 0, stream>>>(Xh, Wht, Qh, Kh, Vt);
    qa_mfma_kernel<<<dim3(16, 16), 256, 0, stream>>>(Qh, akh, QA);
    attn_kernel<<<256, 256, 0, stream>>>(Qh, Kh, Vt, QA, Zt);
    combine_kernel<<<256, 256, 0, stream>>>(Zt, out);
}

// Round 4
// 110.556 us; speedup vs baseline: 4.1555x; 1.0165x over previous
//
#include <hip/hip_runtime.h>
#include <hip/hip_bf16.h>

#define S_LEN 2048
#define E_DIM 512
#define D_DIM 64
#define H_NUM 8
#define B_NUM 2
#define BH_NUM 16
#define NQA 257
#define KSPLIT 4
#define KV_PER (S_LEN / KSPLIT)   // 512 keys per block
#define NT (KV_PER / 64)          // 8 tiles

typedef _Float16 half8 __attribute__((ext_vector_type(8)));
typedef _Float16 half4 __attribute__((ext_vector_type(4)));
typedef float f32x16 __attribute__((ext_vector_type(16)));
typedef unsigned int uint2v __attribute__((ext_vector_type(2)));
typedef unsigned int uint4v __attribute__((ext_vector_type(4)));

static __device__ __forceinline__ f32x16 MFMA(half8 a, half8 b, f32x16 c) {
    return __builtin_amdgcn_mfma_f32_32x32x16_f16(a, b, c, 0, 0, 0);
}
static __device__ __forceinline__ f32x16 ZERO16() {
    f32x16 z;
    #pragma unroll
    for (int i = 0; i < 16; ++i) z[i] = 0.f;
    return z;
}
// cvt_pkrtz returns __fp16x2; bit-cast to u32 immediately (same 4 bytes)
static __device__ __forceinline__ unsigned int PKRTZ(float a, float b) {
    return __builtin_bit_cast(unsigned int, __builtin_amdgcn_cvt_pkrtz(a, b));
}

// ---------------------------------------------------------------------------
// cast xs (fp32) -> Xh (fp16)
// ---------------------------------------------------------------------------
__global__ __launch_bounds__(256) void cast_x_kernel(
    const float* __restrict__ xs, _Float16* __restrict__ Xh)
{
    const int idx = (blockIdx.x * 256 + threadIdx.x) * 8;
    float4 a = *(const float4*)&xs[idx];
    float4 b = *(const float4*)&xs[idx + 4];
    half8 o;
    o[0] = (_Float16)a.x; o[1] = (_Float16)a.y; o[2] = (_Float16)a.z; o[3] = (_Float16)a.w;
    o[4] = (_Float16)b.x; o[5] = (_Float16)b.y; o[6] = (_Float16)b.z; o[7] = (_Float16)b.w;
    *(half8*)&Xh[idx] = o;
}

// ---------------------------------------------------------------------------
// cast + transpose weights -> Wht[type][h][n=64][k=512] fp16  (z = 0,1,2)
// z == 3: cast a_k -> fp16 (first 9 (y*8+x) blocks)
// ---------------------------------------------------------------------------
__global__ __launch_bounds__(256) void cast_wak_kernel(
    const float* __restrict__ w_q, const float* __restrict__ w_k,
    const float* __restrict__ w_v, const float* __restrict__ w_o,
    const float* __restrict__ a_k,
    _Float16* __restrict__ Wht, _Float16* __restrict__ akh)
{
    __shared__ float T[64][68];
    const int type = blockIdx.z;
    const int t = threadIdx.x;
    if (type == 3) {
        const int bn = blockIdx.y * 8 + blockIdx.x;
        if (bn >= 9) return;
        const int idx = (bn * 256 + t) * 8;
        if (idx < NQA * 64) {
            float4 a = *(const float4*)&a_k[idx];
            float4 b = *(const float4*)&a_k[idx + 4];
            half8 o;
            o[0] = (_Float16)a.x; o[1] = (_Float16)a.y; o[2] = (_Float16)a.z; o[3] = (_Float16)a.w;
            o[4] = (_Float16)b.x; o[5] = (_Float16)b.y; o[6] = (_Float16)b.z; o[7] = (_Float16)b.w;
            *(half8*)&akh[idx] = o;
        }
        return;
    }
    const int kt = blockIdx.x, h = blockIdx.y;
    const float* W = (type == 0) ? w_q : (type == 1) ? w_k : w_v;
    const float scale = (type == 0) ? 0.125f : (type == 2 ? w_o[h] : 1.0f);
    const int kr = t >> 2, nseg = (t & 3) * 16;
    #pragma unroll
    for (int i = 0; i < 4; ++i)
        *(float4*)&T[kr][nseg + 4 * i] =
            *(const float4*)&W[((size_t)h * 512 + kt * 64 + kr) * 64 + nseg + 4 * i];
    __syncthreads();
    const int nr = t >> 2, kseg = (t & 3) * 16;
    _Float16* dst = Wht + ((size_t)(type * 8 + h) * 64 + nr) * 512 + kt * 64 + kseg;
    #pragma unroll
    for (int i = 0; i < 2; ++i) {
        half8 o;
        #pragma unroll
        for (int j = 0; j < 8; ++j) o[j] = (_Float16)(T[kseg + 8 * i + j][nr] * scale);
        *(half8*)&dst[8 * i] = o;
    }
}

// ---------------------------------------------------------------------------
// MFMA projections: out[2048x64] = Xh[b] * Wht[type][h]^T   (K=512)
// grid (16 mtiles, 16 bh, 3 type), block 256 (4 waves x 32 rows)
// ---------------------------------------------------------------------------
__global__ __launch_bounds__(256) void proj_mfma_kernel(
    const _Float16* __restrict__ Xh, const _Float16* __restrict__ Wht,
    _Float16* __restrict__ Qh, _Float16* __restrict__ Kh,
    _Float16* __restrict__ Vt)
{
    __shared__ _Float16 Xlds[2][128][72];
    __shared__ _Float16 Wlds[2][64][72];

    const int mt = blockIdx.x, bh = blockIdx.y, type = blockIdx.z;
    const int b = bh >> 3, h = bh & 7;
    const int m0 = mt * 128;
    const int t = threadIdx.x, wid = t >> 6, lane = t & 63;
    const int lq = lane & 31, lh = lane >> 5;

    const _Float16* W = Wht + (size_t)(type * 8 + h) * 64 * 512;
    const _Float16* X = Xh + ((size_t)b * S_LEN + m0) * 512;

    const int xrow = t >> 1, xseg = (t & 1) * 32;
    const int wrow = t >> 2, wseg = (t & 3) * 16;

    #pragma unroll
    for (int i = 0; i < 4; ++i)
        *(half8*)&Xlds[0][xrow][xseg + 8 * i] =
            *(const half8*)&X[(size_t)xrow * 512 + xseg + 8 * i];
    #pragma unroll
    for (int i = 0; i < 2; ++i)
        *(half8*)&Wlds[0][wrow][wseg + 8 * i] =
            *(const half8*)&W[(size_t)wrow * 512 + wseg + 8 * i];
    __syncthreads();

    f32x16 acc[2];
    acc[0] = ZERO16(); acc[1] = ZERO16();
    int cur = 0;
    for (int c = 0; c < 8; ++c) {
        half8 xst[4], wst[2];
        if (c < 7) {
            const int k0 = (c + 1) * 64;
            #pragma unroll
            for (int i = 0; i < 4; ++i)
                xst[i] = *(const half8*)&X[(size_t)xrow * 512 + k0 + xseg + 8 * i];
            #pragma unroll
            for (int i = 0; i < 2; ++i)
                wst[i] = *(const half8*)&W[(size_t)wrow * 512 + k0 + wseg + 8 * i];
        }
        #pragma unroll
        for (int kc = 0; kc < 4; ++kc) {
            half8 a  = *(const half8*)&Xlds[cur][wid * 32 + lq][kc * 16 + lh * 8];
            half8 b0 = *(const half8*)&Wlds[cur][lq][kc * 16 + lh * 8];
            half8 b1 = *(const half8*)&Wlds[cur][32 + lq][kc * 16 + lh * 8];
            acc[0] = MFMA(a, b0, acc[0]);
            acc[1] = MFMA(a, b1, acc[1]);
        }
        if (c < 7) {
            #pragma unroll
            for (int i = 0; i < 4; ++i)
                *(half8*)&Xlds[cur ^ 1][xrow][xseg + 8 * i] = xst[i];
            #pragma unroll
            for (int i = 0; i < 2; ++i)
                *(half8*)&Wlds[cur ^ 1][wrow][wseg + 8 * i] = wst[i];
        }
        __syncthreads();
        cur ^= 1;
    }

    _Float16* ob = &Wlds[0][0][0];
    #pragma unroll
    for (int n = 0; n < 2; ++n)
        #pragma unroll
        for (int r = 0; r < 16; ++r) {
            int row = wid * 32 + (r & 3) + ((r >> 2) << 3) + (lh << 2);
            ob[row * 72 + n * 32 + lq] = (_Float16)acc[n][r];
        }
    __syncthreads();

    if (type == 2) {
        const int v = t >> 2, sseg = (t & 3) * 32;
        _Float16* dst = Vt + ((size_t)bh * 64 + v) * S_LEN + m0 + sseg;
        #pragma unroll
        for (int i = 0; i < 4; ++i) {
            half8 o;
            #pragma unroll
            for (int j = 0; j < 8; ++j) o[j] = ob[(sseg + 8 * i + j) * 72 + v];
            *(half8*)&dst[8 * i] = o;
        }
    } else {
        _Float16* P = (type == 0) ? Qh : Kh;
        const int row = t >> 1, seg = (t & 1) * 32;
        _Float16* dst = P + ((size_t)bh * S_LEN + m0 + row) * 64 + seg;
        #pragma unroll
        for (int i = 0; i < 4; ++i)
            *(half8*)&dst[8 * i] = *(const half8*)&ob[row * 72 + seg + 8 * i];
    }
}

// ---------------------------------------------------------------------------
// MFMA QA: QAh[bh][s][r] = Qh[bh][s][:] . akh[r][:]   (fp16 out, K=64)
// ---------------------------------------------------------------------------
__global__ __launch_bounds__(256) void qa_mfma_kernel(
    const _Float16* __restrict__ Qh, const _Float16* __restrict__ akh,
    _Float16* __restrict__ QAh)
{
    __shared__ _Float16 ak[288][72];
    const int m0 = blockIdx.x * 128, bh = blockIdx.y;
    const int t = threadIdx.x, wid = t >> 6, lane = t & 63;
    const int lq = lane & 31, lh = lane >> 5;

    for (int r = t; r < 288; r += 256) {
        if (r < NQA) {
            #pragma unroll
            for (int i = 0; i < 8; ++i)
                *(half8*)&ak[r][8 * i] = *(const half8*)&akh[(size_t)r * 64 + 8 * i];
        } else {
            half8 z = {};
            #pragma unroll
            for (int i = 0; i < 8; ++i) *(half8*)&ak[r][8 * i] = z;
        }
    }
    __syncthreads();

    const int qg = m0 + wid * 32 + lq;
    half8 qfr[4];
    #pragma unroll
    for (int kc = 0; kc < 4; ++kc)
        qfr[kc] = *(const half8*)&Qh[((size_t)bh * S_LEN + qg) * 64 + kc * 16 + lh * 8];

    for (int nsub = 0; nsub < 9; ++nsub) {
        f32x16 acc = ZERO16();
        #pragma unroll
        for (int kc = 0; kc < 4; ++kc) {
            half8 bf = *(const half8*)&ak[nsub * 32 + lq][kc * 16 + lh * 8];
            acc = MFMA(qfr[kc], bf, acc);
        }
        const int col = nsub * 32 + lq;
        if (col < NQA) {
            #pragma unroll
            for (int r = 0; r < 16; ++r) {
                int row = m0 + wid * 32 + (r & 3) + ((r >> 2) << 3) + (lh << 2);
                QAh[((size_t)bh * S_LEN + row) * NQA + col] = (_Float16)acc[r];
            }
        }
    }
}

// ---------------------------------------------------------------------------
// Flash attention with KV-split partials. grid = 1024 (XCD-swizzled), block 256.
// Each block: 128 q-rows x 512 keys. Writes Po[p][bh][q][v] fp16 (unnormalized)
// + Ml[p][bh][q] = (m, l).
// ---------------------------------------------------------------------------
__global__ __launch_bounds__(256, 3) void attn_kernel(
    const _Float16* __restrict__ Qh, const _Float16* __restrict__ Kh,
    const _Float16* __restrict__ Vt, const _Float16* __restrict__ QAh,
    _Float16* __restrict__ Po, float2* __restrict__ Ml)
{
    __shared__ _Float16 Klds[2][64][72];   // 18432 B (reused as Obuf[128][72])
    __shared__ _Float16 Vlds[2][64][72];

    const int p0 = blockIdx.x;
    const int nb = (p0 & 7) * 128 + (p0 >> 3);   // XCD swizzle: 2 bh per XCD
    const int bh = nb >> 6;
    const int rem = nb & 63;
    const int qt = rem & 15, ks = rem >> 4;
    const int i0 = qt * 128, k0 = ks * KV_PER;

    const int t = threadIdx.x, wid = t >> 6, lane = t & 63;
    const int lq = lane & 31, lh = lane >> 5;
    const int i0w = i0 + wid * 32;
    const int qg = i0w + lq;

    // block-uniform bias mode: 1 = all keys >= q+128, 2 = all keys <= q-128
    int mode = 0;
    if (k0 >= i0 + 255) mode = 1;
    else if (k0 + KV_PER - 1 <= i0 - 128) mode = 2;

    half8 qf[4];
    #pragma unroll
    for (int kc = 0; kc < 4; ++kc)
        qf[kc] = *(const half8*)&Qh[((size_t)bh * S_LEN + qg) * 64 + kc * 16 + lh * 8];

    const _Float16* qaRow = QAh + ((size_t)bh * S_LEN + qg) * NQA;
    const float qa_lo = (float)qaRow[0];
    const float qa_hi = (float)qaRow[256];

    float rm = -1e30f, rl = 0.f;
    f32x16 acco[2];
    acco[0] = ZERO16(); acco[1] = ZERO16();

    const int srow = t >> 2, sseg = (t & 3) * 16;
    const _Float16* Kbase = Kh + ((size_t)bh * S_LEN + k0) * 64;
    const _Float16* Vbase = Vt + ((size_t)bh * 64 + srow) * S_LEN + k0;

    half8 kst0, kst1, vst0, vst1;
    // prologue: tile 0 -> buf0, tile 1 -> regs
    kst0 = *(const half8*)&Kbase[(size_t)srow * 64 + sseg];
    kst1 = *(const half8*)&Kbase[(size_t)srow * 64 + sseg + 8];
    vst0 = *(const half8*)&Vbase[sseg];
    vst1 = *(const half8*)&Vbase[sseg + 8];
    *(half8*)&Klds[0][srow][sseg]     = kst0;
    *(half8*)&Klds[0][srow][sseg + 8] = kst1;
    *(half8*)&Vlds[0][srow][sseg]     = vst0;
    *(half8*)&Vlds[0][srow][sseg + 8] = vst1;
    kst0 = *(const half8*)&Kbase[(size_t)(64 + srow) * 64 + sseg];
    kst1 = *(const half8*)&Kbase[(size_t)(64 + srow) * 64 + sseg + 8];
    vst0 = *(const half8*)&Vbase[64 + sseg];
    vst1 = *(const half8*)&Vbase[64 + sseg + 8];
    __syncthreads();

    for (int jt = 0; jt < NT; ++jt) {
        const int cur = jt & 1;
        if (jt) __syncthreads();
        if (jt + 1 < NT) {                      // stage tile jt+1 -> other buf
            *(half8*)&Klds[cur ^ 1][srow][sseg]     = kst0;
            *(half8*)&Klds[cur ^ 1][srow][sseg + 8] = kst1;
            *(half8*)&Vlds[cur ^ 1][srow][sseg]     = vst0;
            *(half8*)&Vlds[cur ^ 1][srow][sseg + 8] = vst1;
        }
        if (jt + 2 < NT) {                      // issue loads for tile jt+2
            const int jg = (jt + 2) * 64;
            kst0 = *(const half8*)&Kbase[(size_t)(jg + srow) * 64 + sseg];
            kst1 = *(const half8*)&Kbase[(size_t)(jg + srow) * 64 + sseg + 8];
            vst0 = *(const half8*)&Vbase[jg + sseg];
            vst1 = *(const half8*)&Vbase[jg + sseg + 8];
        }

        // S^T = K . Q^T
        f32x16 accs[2];
        accs[0] = ZERO16(); accs[1] = ZERO16();
        #pragma unroll
        for (int kc = 0; kc < 4; ++kc) {
            half8 ka = *(const half8*)&Klds[cur][lq][kc * 16 + lh * 8];
            half8 kb = *(const half8*)&Klds[cur][32 + lq][kc * 16 + lh * 8];
            accs[0] = MFMA(ka, qf[kc], accs[0]);
            accs[1] = MFMA(kb, qf[kc], accs[1]);
        }

        if (mode == 0) {
            const int j0g = k0 + jt * 64;
            const bool allhi = (j0g >= i0w + 159);
            const bool alllo = (j0g + 63 <= i0w - 128);
            if (allhi || alllo) {
                const float bias = allhi ? qa_hi : qa_lo;
                #pragma unroll
                for (int m = 0; m < 2; ++m)
                    #pragma unroll
                    for (int r = 0; r < 16; ++r) accs[m][r] += bias;
            } else {
                #pragma unroll
                for (int m = 0; m < 2; ++m)
                    #pragma unroll
                    for (int r = 0; r < 16; ++r) {
                        int key = j0g + m * 32 + (r & 3) + ((r >> 2) << 3) + (lh << 2);
                        int idx = min(max(key - qg, -128), 128) + 128;
                        accs[m][r] += (float)qaRow[idx];
                    }
            }
        }

        // online softmax (lane owns q-row lq; lh halves synced via xor 32)
        float tmax = -1e30f;
        #pragma unroll
        for (int m = 0; m < 2; ++m)
            #pragma unroll
            for (int r = 0; r < 16; ++r) tmax = fmaxf(tmax, accs[m][r]);
        tmax = fmaxf(tmax, __shfl_xor(tmax, 32));
        const float mnew = fmaxf(rm, tmax);
        const float corr = __expf(rm - mnew);
        rm = mnew;

        float psum = 0.f;
        #pragma unroll
        for (int m = 0; m < 2; ++m)
            #pragma unroll
            for (int r = 0; r < 16; ++r) {
                float p = __expf(accs[m][r] - mnew);
                accs[m][r] = p;
                psum += p;
            }
        psum += __shfl_xor(psum, 32);
        rl = rl * corr + psum;
        #pragma unroll
        for (int n = 0; n < 2; ++n)
            #pragma unroll
            for (int r = 0; r < 16; ++r) acco[n][r] *= corr;

        // pack P -> PV B-fragments in-register (cvt_pkrtz + permlane32_swap)
        half8 pf[4];
        #pragma unroll
        for (int kc = 0; kc < 4; ++kc) {
            const int m = kc >> 1, rb = (kc & 1) * 8;
            unsigned int a01 = PKRTZ(accs[m][rb + 0], accs[m][rb + 1]);
            unsigned int a45 = PKRTZ(accs[m][rb + 4], accs[m][rb + 5]);
            unsigned int a23 = PKRTZ(accs[m][rb + 2], accs[m][rb + 3]);
            unsigned int a67 = PKRTZ(accs[m][rb + 6], accs[m][rb + 7]);
            uint2v r02 = __builtin_amdgcn_permlane32_swap(a01, a45, false, false);
            uint2v r13 = __builtin_amdgcn_permlane32_swap(a23, a67, false, false);
            uint4v wv;
            wv[0] = r02[0]; wv[1] = r13[0]; wv[2] = r02[1]; wv[3] = r13[1];
            pf[kc] = __builtin_bit_cast(half8, wv);
        }

        // O^T += V^T . P^T
        #pragma unroll
        for (int kc = 0; kc < 4; ++kc) {
            half8 v0 = *(const half8*)&Vlds[cur][lq][kc * 16 + lh * 8];
            half8 v1 = *(const half8*)&Vlds[cur][32 + lq][kc * 16 + lh * 8];
            acco[0] = MFMA(v0, pf[kc], acco[0]);
            acco[1] = MFMA(v1, pf[kc], acco[1]);
        }
    }

    // epilogue: transpose acco via LDS overlay -> coalesced fp16 Po[q][v]
    __syncthreads();
    _Float16* Obuf = &Klds[0][0][0];          // [128][72]
    const float rmS = rm + (mode == 1 ? qa_hi : (mode == 2 ? qa_lo : 0.f));
    const int orow = wid * 32 + lq;
    #pragma unroll
    for (int n = 0; n < 2; ++n)
        #pragma unroll
        for (int rq = 0; rq < 4; ++rq) {
            unsigned int p01 = PKRTZ(acco[n][rq * 4 + 0], acco[n][rq * 4 + 1]);
            unsigned int p23 = PKRTZ(acco[n][rq * 4 + 2], acco[n][rq * 4 + 3]);
            uint2v hv;
            hv[0] = p01; hv[1] = p23;
            *(uint2v*)&Obuf[(size_t)orow * 72 + n * 32 + rq * 8 + lh * 4] = hv;
        }
    if (lh == 0)
        Ml[((size_t)ks * BH_NUM + bh) * S_LEN + qg] = make_float2(rmS, rl);
    asm volatile("s_waitcnt lgkmcnt(0)" ::: "memory");
    __builtin_amdgcn_sched_barrier(0);
    const int rrow = wid * 32 + ((t & 63) >> 1);
    const int rseg = (t & 1) * 32;
    _Float16* dst = Po + (((size_t)ks * BH_NUM + bh) * S_LEN + i0 + rrow) * 64 + rseg;
    #pragma unroll
    for (int i = 0; i < 4; ++i)
        *(half8*)&dst[8 * i] = *(const half8*)&Obuf[(size_t)rrow * 72 + rseg + 8 * i];
}

// ---------------------------------------------------------------------------
// merge partials + combine heads:
// out[b][s][v] = sum_h (sum_p e^{m_p-M} O_p) / (sum_p e^{m_p-M} l_p)
// grid (64, 2), block 256: 32 s-rows x 8 v-groups of 8
// ---------------------------------------------------------------------------
__global__ __launch_bounds__(256) void merge_kernel(
    const _Float16* __restrict__ Po, const float2* __restrict__ Ml,
    float* __restrict__ out)
{
    const int b = blockIdx.y;
    const int s = blockIdx.x * 32 + (threadIdx.x >> 3);
    const int v0 = (threadIdx.x & 7) * 8;
    float acc[8] = {0, 0, 0, 0, 0, 0, 0, 0};
    #pragma unroll
    for (int h = 0; h < 8; ++h) {
        const int bh = b * 8 + h;
        float m[KSPLIT], l[KSPLIT];
        #pragma unroll
        for (int p = 0; p < KSPLIT; ++p) {
            const float2 v = Ml[((size_t)p * BH_NUM + bh) * S_LEN + s];
            m[p] = v.x; l[p] = v.y;
        }
        float M = fmaxf(fmaxf(m[0], m[1]), fmaxf(m[2], m[3]));
        float L = 0.f, w[KSPLIT];
        #pragma unroll
        for (int p = 0; p < KSPLIT; ++p) { w[p] = __expf(m[p] - M); L += w[p] * l[p]; }
        const float invL = 1.0f / L;
        #pragma unroll
        for (int p = 0; p < KSPLIT; ++p) {
            half8 o = *(const half8*)&Po[(((size_t)p * BH_NUM + bh) * S_LEN + s) * 64 + v0];
            const float wp = w[p] * invL;
            #pragma unroll
            for (int j = 0; j < 8; ++j) acc[j] += wp * (float)o[j];
        }
    }
    float4 o0 = {acc[0], acc[1], acc[2], acc[3]};
    float4 o1 = {acc[4], acc[5], acc[6], acc[7]};
    *(float4*)&out[((size_t)b * S_LEN + s) * 64 + v0] = o0;
    *(float4*)&out[((size_t)b * S_LEN + s) * 64 + v0 + 4] = o1;
}

// ---------------------------------------------------------------------------
extern "C" void kernel_launch(void* const* d_in, const int* in_sizes, int n_in,
                              void* d_out, int out_size, void* d_ws, size_t ws_size,
                              hipStream_t stream)
{
    const float* xs  = (const float*)d_in[0];
    const float* w_q = (const float*)d_in[1];
    const float* w_k = (const float*)d_in[2];
    const float* w_v = (const float*)d_in[3];
    const float* w_o = (const float*)d_in[4];
    const float* a_k = (const float*)d_in[5];
    float* out = (float*)d_out;

    char* w = (char*)d_ws;
    _Float16* Xh  = (_Float16*)w;  w += (size_t)B_NUM * S_LEN * E_DIM * 2;      // 4 MB
    _Float16* Wht = (_Float16*)w;  w += (size_t)3 * H_NUM * 64 * 512 * 2;       // 1.5 MB
    _Float16* akh = (_Float16*)w;  w += 33024;
    _Float16* Qh  = (_Float16*)w;  w += (size_t)BH_NUM * S_LEN * 64 * 2;
    _Float16* Kh  = (_Float16*)w;  w += (size_t)BH_NUM * S_LEN * 64 * 2;
    _Float16* Vt  = (_Float16*)w;  w += (size_t)BH_NUM * S_LEN * 64 * 2;
    _Float16* QAh = (_Float16*)w;  w += (size_t)BH_NUM * S_LEN * NQA * 2;       // 16.8 MB
    _Float16* Po  = (_Float16*)w;  w += (size_t)KSPLIT * BH_NUM * S_LEN * 64 * 2; // 16 MB
    float2*   Ml  = (float2*)w;                                                  // 1 MB

    cast_x_kernel<<<1024, 256, 0, stream>>>(xs, Xh);
    cast_wak_kernel<<<dim3(8, 8, 4), 256, 0, stream>>>(w_q, w_k, w_v, w_o, a_k, Wht, akh);
    proj_mfma_kernel<<<dim3(16, 16, 3), 256, 0, stream>>>(Xh, Wht, Qh, Kh, Vt);
    qa_mfma_kernel<<<dim3(16, 16), 256, 0, stream>>>(Qh, akh, QAh);
    attn_kernel<<<1024, 256, 0, stream>>>(Qh, Kh, Vt, QAh, Po, Ml);
    merge_kernel<<<dim3(64, 2), 256, 0, stream>>>(Po, Ml, out);
}

// Round 5
// 103.232 us; speedup vs baseline: 4.4503x; 1.0709x over previous
//
#include <hip/hip_runtime.h>
#include <hip/hip_bf16.h>

#define S_LEN 2048
#define E_DIM 512
#define D_DIM 64
#define H_NUM 8
#define B_NUM 2
#define BH_NUM 16
#define NQA 257
#define KSPLIT 2
#define KV_PER (S_LEN / KSPLIT)   // 1024 keys per block
#define NT (KV_PER / 64)          // 16 tiles

typedef _Float16 half8 __attribute__((ext_vector_type(8)));
typedef _Float16 half4 __attribute__((ext_vector_type(4)));
typedef float f32x16 __attribute__((ext_vector_type(16)));
typedef unsigned int uint2v __attribute__((ext_vector_type(2)));
typedef unsigned int uint4v __attribute__((ext_vector_type(4)));

static __device__ __forceinline__ f32x16 MFMA(half8 a, half8 b, f32x16 c) {
    return __builtin_amdgcn_mfma_f32_32x32x16_f16(a, b, c, 0, 0, 0);
}
static __device__ __forceinline__ f32x16 ZERO16() {
    f32x16 z;
    #pragma unroll
    for (int i = 0; i < 16; ++i) z[i] = 0.f;
    return z;
}
// cvt_pkrtz returns __fp16x2; bit-cast to u32 immediately (same 4 bytes)
static __device__ __forceinline__ unsigned int PKRTZ(float a, float b) {
    return __builtin_bit_cast(unsigned int, __builtin_amdgcn_cvt_pkrtz(a, b));
}

// ---------------------------------------------------------------------------
// cast xs (fp32) -> Xh (fp16)
// ---------------------------------------------------------------------------
__global__ __launch_bounds__(256) void cast_x_kernel(
    const float* __restrict__ xs, _Float16* __restrict__ Xh)
{
    const int idx = (blockIdx.x * 256 + threadIdx.x) * 8;
    float4 a = *(const float4*)&xs[idx];
    float4 b = *(const float4*)&xs[idx + 4];
    half8 o;
    o[0] = (_Float16)a.x; o[1] = (_Float16)a.y; o[2] = (_Float16)a.z; o[3] = (_Float16)a.w;
    o[4] = (_Float16)b.x; o[5] = (_Float16)b.y; o[6] = (_Float16)b.z; o[7] = (_Float16)b.w;
    *(half8*)&Xh[idx] = o;
}

// ---------------------------------------------------------------------------
// cast + transpose weights -> Wht[type][h][n=64][k=512] fp16  (z = 0,1,2)
// z == 3: cast a_k -> fp16 (first 9 (y*8+x) blocks)
// ---------------------------------------------------------------------------
__global__ __launch_bounds__(256) void cast_wak_kernel(
    const float* __restrict__ w_q, const float* __restrict__ w_k,
    const float* __restrict__ w_v, const float* __restrict__ w_o,
    const float* __restrict__ a_k,
    _Float16* __restrict__ Wht, _Float16* __restrict__ akh)
{
    __shared__ float T[64][68];
    const int type = blockIdx.z;
    const int t = threadIdx.x;
    if (type == 3) {
        const int bn = blockIdx.y * 8 + blockIdx.x;
        if (bn >= 9) return;
        const int idx = (bn * 256 + t) * 8;
        if (idx < NQA * 64) {
            float4 a = *(const float4*)&a_k[idx];
            float4 b = *(const float4*)&a_k[idx + 4];
            half8 o;
            o[0] = (_Float16)a.x; o[1] = (_Float16)a.y; o[2] = (_Float16)a.z; o[3] = (_Float16)a.w;
            o[4] = (_Float16)b.x; o[5] = (_Float16)b.y; o[6] = (_Float16)b.z; o[7] = (_Float16)b.w;
            *(half8*)&akh[idx] = o;
        }
        return;
    }
    const int kt = blockIdx.x, h = blockIdx.y;
    const float* W = (type == 0) ? w_q : (type == 1) ? w_k : w_v;
    const float scale = (type == 0) ? 0.125f : (type == 2 ? w_o[h] : 1.0f);
    const int kr = t >> 2, nseg = (t & 3) * 16;
    #pragma unroll
    for (int i = 0; i < 4; ++i)
        *(float4*)&T[kr][nseg + 4 * i] =
            *(const float4*)&W[((size_t)h * 512 + kt * 64 + kr) * 64 + nseg + 4 * i];
    __syncthreads();
    const int nr = t >> 2, kseg = (t & 3) * 16;
    _Float16* dst = Wht + ((size_t)(type * 8 + h) * 64 + nr) * 512 + kt * 64 + kseg;
    #pragma unroll
    for (int i = 0; i < 2; ++i) {
        half8 o;
        #pragma unroll
        for (int j = 0; j < 8; ++j) o[j] = (_Float16)(T[kseg + 8 * i + j][nr] * scale);
        *(half8*)&dst[8 * i] = o;
    }
}

// ---------------------------------------------------------------------------
// MFMA projections: out[2048x64] = Xh[b] * Wht[type][h]^T   (K=512)
// grid (16 mtiles, 16 bh, 3 type), block 256 (4 waves x 32 rows)
// ---------------------------------------------------------------------------
__global__ __launch_bounds__(256) void proj_mfma_kernel(
    const _Float16* __restrict__ Xh, const _Float16* __restrict__ Wht,
    _Float16* __restrict__ Qh, _Float16* __restrict__ Kh,
    _Float16* __restrict__ Vt)
{
    __shared__ _Float16 Xlds[2][128][72];
    __shared__ _Float16 Wlds[2][64][72];

    const int mt = blockIdx.x, bh = blockIdx.y, type = blockIdx.z;
    const int b = bh >> 3, h = bh & 7;
    const int m0 = mt * 128;
    const int t = threadIdx.x, wid = t >> 6, lane = t & 63;
    const int lq = lane & 31, lh = lane >> 5;

    const _Float16* W = Wht + (size_t)(type * 8 + h) * 64 * 512;
    const _Float16* X = Xh + ((size_t)b * S_LEN + m0) * 512;

    const int xrow = t >> 1, xseg = (t & 1) * 32;
    const int wrow = t >> 2, wseg = (t & 3) * 16;

    #pragma unroll
    for (int i = 0; i < 4; ++i)
        *(half8*)&Xlds[0][xrow][xseg + 8 * i] =
            *(const half8*)&X[(size_t)xrow * 512 + xseg + 8 * i];
    #pragma unroll
    for (int i = 0; i < 2; ++i)
        *(half8*)&Wlds[0][wrow][wseg + 8 * i] =
            *(const half8*)&W[(size_t)wrow * 512 + wseg + 8 * i];
    __syncthreads();

    f32x16 acc[2];
    acc[0] = ZERO16(); acc[1] = ZERO16();
    int cur = 0;
    for (int c = 0; c < 8; ++c) {
        half8 xst[4], wst[2];
        if (c < 7) {
            const int k0 = (c + 1) * 64;
            #pragma unroll
            for (int i = 0; i < 4; ++i)
                xst[i] = *(const half8*)&X[(size_t)xrow * 512 + k0 + xseg + 8 * i];
            #pragma unroll
            for (int i = 0; i < 2; ++i)
                wst[i] = *(const half8*)&W[(size_t)wrow * 512 + k0 + wseg + 8 * i];
        }
        #pragma unroll
        for (int kc = 0; kc < 4; ++kc) {
            half8 a  = *(const half8*)&Xlds[cur][wid * 32 + lq][kc * 16 + lh * 8];
            half8 b0 = *(const half8*)&Wlds[cur][lq][kc * 16 + lh * 8];
            half8 b1 = *(const half8*)&Wlds[cur][32 + lq][kc * 16 + lh * 8];
            acc[0] = MFMA(a, b0, acc[0]);
            acc[1] = MFMA(a, b1, acc[1]);
        }
        if (c < 7) {
            #pragma unroll
            for (int i = 0; i < 4; ++i)
                *(half8*)&Xlds[cur ^ 1][xrow][xseg + 8 * i] = xst[i];
            #pragma unroll
            for (int i = 0; i < 2; ++i)
                *(half8*)&Wlds[cur ^ 1][wrow][wseg + 8 * i] = wst[i];
        }
        __syncthreads();
        cur ^= 1;
    }

    _Float16* ob = &Wlds[0][0][0];
    #pragma unroll
    for (int n = 0; n < 2; ++n)
        #pragma unroll
        for (int r = 0; r < 16; ++r) {
            int row = wid * 32 + (r & 3) + ((r >> 2) << 3) + (lh << 2);
            ob[row * 72 + n * 32 + lq] = (_Float16)acc[n][r];
        }
    __syncthreads();

    if (type == 2) {
        const int v = t >> 2, sseg = (t & 3) * 32;
        _Float16* dst = Vt + ((size_t)bh * 64 + v) * S_LEN + m0 + sseg;
        #pragma unroll
        for (int i = 0; i < 4; ++i) {
            half8 o;
            #pragma unroll
            for (int j = 0; j < 8; ++j) o[j] = ob[(sseg + 8 * i + j) * 72 + v];
            *(half8*)&dst[8 * i] = o;
        }
    } else {
        _Float16* P = (type == 0) ? Qh : Kh;
        const int row = t >> 1, seg = (t & 1) * 32;
        _Float16* dst = P + ((size_t)bh * S_LEN + m0 + row) * 64 + seg;
        #pragma unroll
        for (int i = 0; i < 4; ++i)
            *(half8*)&dst[8 * i] = *(const half8*)&ob[row * 72 + seg + 8 * i];
    }
}

// ---------------------------------------------------------------------------
// MFMA QA: QAh[bh][s][r] = Qh[bh][s][:] . akh[r][:]   (fp16 out, K=64)
// ---------------------------------------------------------------------------
__global__ __launch_bounds__(256) void qa_mfma_kernel(
    const _Float16* __restrict__ Qh, const _Float16* __restrict__ akh,
    _Float16* __restrict__ QAh)
{
    __shared__ _Float16 ak[288][72];
    const int m0 = blockIdx.x * 128, bh = blockIdx.y;
    const int t = threadIdx.x, wid = t >> 6, lane = t & 63;
    const int lq = lane & 31, lh = lane >> 5;

    for (int r = t; r < 288; r += 256) {
        if (r < NQA) {
            #pragma unroll
            for (int i = 0; i < 8; ++i)
                *(half8*)&ak[r][8 * i] = *(const half8*)&akh[(size_t)r * 64 + 8 * i];
        } else {
            half8 z = {};
            #pragma unroll
            for (int i = 0; i < 8; ++i) *(half8*)&ak[r][8 * i] = z;
        }
    }
    __syncthreads();

    const int qg = m0 + wid * 32 + lq;
    half8 qfr[4];
    #pragma unroll
    for (int kc = 0; kc < 4; ++kc)
        qfr[kc] = *(const half8*)&Qh[((size_t)bh * S_LEN + qg) * 64 + kc * 16 + lh * 8];

    for (int nsub = 0; nsub < 9; ++nsub) {
        f32x16 acc = ZERO16();
        #pragma unroll
        for (int kc = 0; kc < 4; ++kc) {
            half8 bf = *(const half8*)&ak[nsub * 32 + lq][kc * 16 + lh * 8];
            acc = MFMA(qfr[kc], bf, acc);
        }
        const int col = nsub * 32 + lq;
        if (col < NQA) {
            #pragma unroll
            for (int r = 0; r < 16; ++r) {
                int row = m0 + wid * 32 + (r & 3) + ((r >> 2) << 3) + (lh << 2);
                QAh[((size_t)bh * S_LEN + row) * NQA + col] = (_Float16)acc[r];
            }
        }
    }
}

// ---------------------------------------------------------------------------
// Flash attention, 512-thread blocks (8 waves x 32 q-rows = 256 q-rows),
// KSPLIT=2, grid = 16 bh x 8 qt x 2 ks = 256 blocks (XCD-swizzled).
// K/V double-buffered in 36.9KB LDS shared by all 8 waves; epilogue O-buffer
// overlays the same LDS. Writes Po[p][bh][q][v] fp16 + Ml[p][bh][q]=(m,l).
// ---------------------------------------------------------------------------
__global__ __launch_bounds__(512) void attn_kernel(
    const _Float16* __restrict__ Qh, const _Float16* __restrict__ Kh,
    const _Float16* __restrict__ Vt, const _Float16* __restrict__ QAh,
    _Float16* __restrict__ Po, float2* __restrict__ Ml)
{
    __shared__ __align__(16) char smraw[36864];
    _Float16 (*Klds)[64][72] = (_Float16(*)[64][72])smraw;             // [2][64][72]
    _Float16 (*Vlds)[64][72] = (_Float16(*)[64][72])(smraw + 18432);   // [2][64][72]
    _Float16* Obuf = (_Float16*)smraw;                                 // [256][72]

    const int p0 = blockIdx.x;                 // 0..255
    const int nb = (p0 & 7) * 32 + (p0 >> 3);  // XCD swizzle: 2 bh per XCD
    const int bh = nb >> 4;
    const int rem = nb & 15;
    const int qt = rem & 7, ks = rem >> 3;
    const int i0 = qt * 256, k0 = ks * KV_PER;

    const int t = threadIdx.x, wid = t >> 6, lane = t & 63;
    const int lq = lane & 31, lh = lane >> 5;
    const int i0w = i0 + wid * 32;             // this wave's 32 q-rows
    const int qg = i0w + lq;

    // block-uniform bias mode over the 256-row q-tile:
    // 1 = all keys clip at +128, 2 = all keys clip at -128
    int mode = 0;
    if (k0 >= i0 + 383) mode = 1;
    else if (k0 + KV_PER - 1 <= i0 - 128) mode = 2;

    half8 qf[4];
    #pragma unroll
    for (int kc = 0; kc < 4; ++kc)
        qf[kc] = *(const half8*)&Qh[((size_t)bh * S_LEN + qg) * 64 + kc * 16 + lh * 8];

    const _Float16* qaRow = QAh + ((size_t)bh * S_LEN + qg) * NQA;
    const float qa_lo = (float)qaRow[0];
    const float qa_hi = (float)qaRow[256];

    float rm = -1e30f, rl = 0.f;
    f32x16 acco[2];
    acco[0] = ZERO16(); acco[1] = ZERO16();

    // staging: 512 threads, each 16B of K-tile and 16B of Vt-tile per KV tile
    const int srow = t >> 3, sseg = (t & 7) * 8;
    const _Float16* Kbase = Kh + ((size_t)bh * S_LEN + k0) * 64;
    const _Float16* Vbase = Vt + ((size_t)bh * 64 + srow) * S_LEN + k0;

    half8 kst, vst;
    // prologue: tile 0 -> buf0, tile 1 -> regs
    *(half8*)&Klds[0][srow][sseg] = *(const half8*)&Kbase[(size_t)srow * 64 + sseg];
    *(half8*)&Vlds[0][srow][sseg] = *(const half8*)&Vbase[sseg];
    kst = *(const half8*)&Kbase[(size_t)(64 + srow) * 64 + sseg];
    vst = *(const half8*)&Vbase[64 + sseg];
    __syncthreads();

    for (int jt = 0; jt < NT; ++jt) {
        const int cur = jt & 1;
        if (jt) __syncthreads();
        if (jt + 1 < NT) {                      // stage tile jt+1 -> other buf
            *(half8*)&Klds[cur ^ 1][srow][sseg] = kst;
            *(half8*)&Vlds[cur ^ 1][srow][sseg] = vst;
        }
        if (jt + 2 < NT) {                      // issue loads for tile jt+2
            const int jg = (jt + 2) * 64;
            kst = *(const half8*)&Kbase[(size_t)(jg + srow) * 64 + sseg];
            vst = *(const half8*)&Vbase[jg + sseg];
        }

        // S^T = K . Q^T
        f32x16 accs[2];
        accs[0] = ZERO16(); accs[1] = ZERO16();
        __builtin_amdgcn_s_setprio(1);
        #pragma unroll
        for (int kc = 0; kc < 4; ++kc) {
            half8 ka = *(const half8*)&Klds[cur][lq][kc * 16 + lh * 8];
            half8 kb = *(const half8*)&Klds[cur][32 + lq][kc * 16 + lh * 8];
            accs[0] = MFMA(ka, qf[kc], accs[0]);
            accs[1] = MFMA(kb, qf[kc], accs[1]);
        }
        __builtin_amdgcn_s_setprio(0);

        if (mode == 0) {
            const int j0g = k0 + jt * 64;
            const bool allhi = (j0g >= i0w + 159);
            const bool alllo = (j0g + 63 <= i0w - 128);
            if (allhi || alllo) {
                const float bias = allhi ? qa_hi : qa_lo;
                #pragma unroll
                for (int m = 0; m < 2; ++m)
                    #pragma unroll
                    for (int r = 0; r < 16; ++r) accs[m][r] += bias;
            } else {
                #pragma unroll
                for (int m = 0; m < 2; ++m)
                    #pragma unroll
                    for (int r = 0; r < 16; ++r) {
                        int key = j0g + m * 32 + (r & 3) + ((r >> 2) << 3) + (lh << 2);
                        int idx = min(max(key - qg, -128), 128) + 128;
                        accs[m][r] += (float)qaRow[idx];
                    }
            }
        }

        // online softmax (lane owns q-row lq; lh halves synced via xor 32)
        float tmax = -1e30f;
        #pragma unroll
        for (int m = 0; m < 2; ++m)
            #pragma unroll
            for (int r = 0; r < 16; ++r) tmax = fmaxf(tmax, accs[m][r]);
        tmax = fmaxf(tmax, __shfl_xor(tmax, 32));
        const float mnew = fmaxf(rm, tmax);
        const float corr = __expf(rm - mnew);
        rm = mnew;

        float psum = 0.f;
        #pragma unroll
        for (int m = 0; m < 2; ++m)
            #pragma unroll
            for (int r = 0; r < 16; ++r) {
                float p = __expf(accs[m][r] - mnew);
                accs[m][r] = p;
                psum += p;
            }
        psum += __shfl_xor(psum, 32);
        rl = rl * corr + psum;
        #pragma unroll
        for (int n = 0; n < 2; ++n)
            #pragma unroll
            for (int r = 0; r < 16; ++r) acco[n][r] *= corr;

        // pack P -> PV B-fragments in-register (cvt_pkrtz + permlane32_swap)
        half8 pf[4];
        #pragma unroll
        for (int kc = 0; kc < 4; ++kc) {
            const int m = kc >> 1, rb = (kc & 1) * 8;
            unsigned int a01 = PKRTZ(accs[m][rb + 0], accs[m][rb + 1]);
            unsigned int a45 = PKRTZ(accs[m][rb + 4], accs[m][rb + 5]);
            unsigned int a23 = PKRTZ(accs[m][rb + 2], accs[m][rb + 3]);
            unsigned int a67 = PKRTZ(accs[m][rb + 6], accs[m][rb + 7]);
            uint2v r02 = __builtin_amdgcn_permlane32_swap(a01, a45, false, false);
            uint2v r13 = __builtin_amdgcn_permlane32_swap(a23, a67, false, false);
            uint4v wv;
            wv[0] = r02[0]; wv[1] = r13[0]; wv[2] = r02[1]; wv[3] = r13[1];
            pf[kc] = __builtin_bit_cast(half8, wv);
        }

        // O^T += V^T . P^T
        __builtin_amdgcn_s_setprio(1);
        #pragma unroll
        for (int kc = 0; kc < 4; ++kc) {
            half8 v0 = *(const half8*)&Vlds[cur][lq][kc * 16 + lh * 8];
            half8 v1 = *(const half8*)&Vlds[cur][32 + lq][kc * 16 + lh * 8];
            acco[0] = MFMA(v0, pf[kc], acco[0]);
            acco[1] = MFMA(v1, pf[kc], acco[1]);
        }
        __builtin_amdgcn_s_setprio(0);
    }

    // epilogue: all waves done with K/V LDS -> overlay O-buffer
    __syncthreads();
    const float rmS = rm + (mode == 1 ? qa_hi : (mode == 2 ? qa_lo : 0.f));
    const int orow = wid * 32 + lq;
    #pragma unroll
    for (int n = 0; n < 2; ++n)
        #pragma unroll
        for (int rq = 0; rq < 4; ++rq) {
            unsigned int p01 = PKRTZ(acco[n][rq * 4 + 0], acco[n][rq * 4 + 1]);
            unsigned int p23 = PKRTZ(acco[n][rq * 4 + 2], acco[n][rq * 4 + 3]);
            uint2v hv;
            hv[0] = p01; hv[1] = p23;
            *(uint2v*)&Obuf[(size_t)orow * 72 + n * 32 + rq * 8 + lh * 4] = hv;
        }
    if (lh == 0)
        Ml[((size_t)ks * BH_NUM + bh) * S_LEN + qg] = make_float2(rmS, rl);
    // wave-synchronous LDS: each wave reads back only its own 32 rows
    asm volatile("s_waitcnt lgkmcnt(0)" ::: "memory");
    __builtin_amdgcn_sched_barrier(0);
    const int rrow = wid * 32 + (lane >> 1);
    const int rseg = (lane & 1) * 32;
    _Float16* dst = Po + (((size_t)ks * BH_NUM + bh) * S_LEN + i0 + rrow) * 64 + rseg;
    #pragma unroll
    for (int i = 0; i < 4; ++i)
        *(half8*)&dst[8 * i] = *(const half8*)&Obuf[(size_t)rrow * 72 + rseg + 8 * i];
}

// ---------------------------------------------------------------------------
// merge partials + combine heads:
// out[b][s][v] = sum_h (sum_p e^{m_p-M} O_p) / (sum_p e^{m_p-M} l_p)
// grid (64, 2), block 256: 32 s-rows x 8 v-groups of 8
// ---------------------------------------------------------------------------
__global__ __launch_bounds__(256) void merge_kernel(
    const _Float16* __restrict__ Po, const float2* __restrict__ Ml,
    float* __restrict__ out)
{
    const int b = blockIdx.y;
    const int s = blockIdx.x * 32 + (threadIdx.x >> 3);
    const int v0 = (threadIdx.x & 7) * 8;
    float acc[8] = {0, 0, 0, 0, 0, 0, 0, 0};
    #pragma unroll
    for (int h = 0; h < 8; ++h) {
        const int bh = b * 8 + h;
        float m[KSPLIT], l[KSPLIT];
        #pragma unroll
        for (int p = 0; p < KSPLIT; ++p) {
            const float2 v = Ml[((size_t)p * BH_NUM + bh) * S_LEN + s];
            m[p] = v.x; l[p] = v.y;
        }
        float M = fmaxf(m[0], m[1]);
        float L = 0.f, w[KSPLIT];
        #pragma unroll
        for (int p = 0; p < KSPLIT; ++p) { w[p] = __expf(m[p] - M); L += w[p] * l[p]; }
        const float invL = 1.0f / L;
        #pragma unroll
        for (int p = 0; p < KSPLIT; ++p) {
            half8 o = *(const half8*)&Po[(((size_t)p * BH_NUM + bh) * S_LEN + s) * 64 + v0];
            const float wp = w[p] * invL;
            #pragma unroll
            for (int j = 0; j < 8; ++j) acc[j] += wp * (float)o[j];
        }
    }
    float4 o0 = {acc[0], acc[1], acc[2], acc[3]};
    float4 o1 = {acc[4], acc[5], acc[6], acc[7]};
    *(float4*)&out[((size_t)b * S_LEN + s) * 64 + v0] = o0;
    *(float4*)&out[((size_t)b * S_LEN + s) * 64 + v0 + 4] = o1;
}

// ---------------------------------------------------------------------------
extern "C" void kernel_launch(void* const* d_in, const int* in_sizes, int n_in,
                              void* d_out, int out_size, void* d_ws, size_t ws_size,
                              hipStream_t stream)
{
    const float* xs  = (const float*)d_in[0];
    const float* w_q = (const float*)d_in[1];
    const float* w_k = (const float*)d_in[2];
    const float* w_v = (const float*)d_in[3];
    const float* w_o = (const float*)d_in[4];
    const float* a_k = (const float*)d_in[5];
    float* out = (float*)d_out;

    char* w = (char*)d_ws;
    _Float16* Xh  = (_Float16*)w;  w += (size_t)B_NUM * S_LEN * E_DIM * 2;        // 4 MB
    _Float16* Wht = (_Float16*)w;  w += (size_t)3 * H_NUM * 64 * 512 * 2;         // 1.5 MB
    _Float16* akh = (_Float16*)w;  w += 33024;
    _Float16* Qh  = (_Float16*)w;  w += (size_t)BH_NUM * S_LEN * 64 * 2;
    _Float16* Kh  = (_Float16*)w;  w += (size_t)BH_NUM * S_LEN * 64 * 2;
    _Float16* Vt  = (_Float16*)w;  w += (size_t)BH_NUM * S_LEN * 64 * 2;
    _Float16* QAh = (_Float16*)w;  w += (size_t)BH_NUM * S_LEN * NQA * 2;         // 16.8 MB
    _Float16* Po  = (_Float16*)w;  w += (size_t)KSPLIT * BH_NUM * S_LEN * 64 * 2; // 8.4 MB
    float2*   Ml  = (float2*)w;                                                    // 0.5 MB

    cast_x_kernel<<<1024, 256, 0, stream>>>(xs, Xh);
    cast_wak_kernel<<<dim3(8, 8, 4), 256, 0, stream>>>(w_q, w_k, w_v, w_o, a_k, Wht, akh);
    proj_mfma_kernel<<<dim3(16, 16, 3), 256, 0, stream>>>(Xh, Wht, Qh, Kh, Vt);
    qa_mfma_kernel<<<dim3(16, 16), 256, 0, stream>>>(Qh, akh, QAh);
    attn_kernel<<<256, 512, 0, stream>>>(Qh, Kh, Vt, QAh, Po, Ml);
    merge_kernel<<<dim3(64, 2), 256, 0, stream>>>(Po, Ml, out);
}